// Round 1
// baseline (198.728 us; speedup 1.0000x reference)
//
#include <hip/hip_runtime.h>

#define WIN 33
#define WIDTH 128
#define MPTS 64
#define NN 2048
#define MM 2048
#define DD 64
#define NQ 2080   // N + 2L

typedef __bf16 bf16x8 __attribute__((ext_vector_type(8)));
typedef float f32x4 __attribute__((ext_vector_type(4)));

__device__ __forceinline__ unsigned short f2bf(float x) {
  union { float f; unsigned int u; } v; v.f = x;
  unsigned int r = v.u + 0x7FFFu + ((v.u >> 16) & 1u);  // RNE
  return (unsigned short)(r >> 16);
}
__device__ __forceinline__ float sigf(float x) { return 1.0f / (1.0f + __expf(-x)); }

// ------------- xi[M][NQ] f32  ->  xiT[NQ][M] bf16 (transpose + convert) ----
__global__ __launch_bounds__(256) void k_transpose(const float* __restrict__ xi,
                                                   unsigned short* __restrict__ xiT) {
  __shared__ float t[32][33];
  int qb = blockIdx.x * 32;   // 65 tiles over NQ=2080
  int mb = blockIdx.y * 32;   // 64 tiles over M=2048
  int c = threadIdx.x & 31, r0 = threadIdx.x >> 5;
#pragma unroll
  for (int it = 0; it < 4; ++it) {
    int r = r0 + it * 8;
    t[r][c] = xi[(size_t)(mb + r) * NQ + qb + c];
  }
  __syncthreads();
#pragma unroll
  for (int it = 0; it < 4; ++it) {
    int r = r0 + it * 8;
    xiT[(size_t)(qb + r) * MM + mb + c] = f2bf(t[c][r]);
  }
}

// ------------- layer0: u1[j][k][p] = sig(dot64(w0[j][k], u[p]) + b0) -------
__global__ __launch_bounds__(256) void k_layer0(const float* __restrict__ u,
                                                const float* __restrict__ w0,
                                                const float* __restrict__ b0,
                                                float* __restrict__ out) {
  int b = blockIdx.x;                      // 33*32 blocks
  int j = b >> 5;
  int k = ((b & 31) << 2) + (threadIdx.x >> 6);
  int p = threadIdx.x & 63;
  const float* wr = w0 + (size_t)(j * WIDTH + k) * DD;
  const float* ur = u + (size_t)p * DD;
  float acc = b0[j * WIDTH + k];
#pragma unroll
  for (int l = 0; l < DD; l += 4) {
    float4 wv = *(const float4*)(wr + l);
    float4 uv = *(const float4*)(ur + l);
    acc += wv.x * uv.x + wv.y * uv.y + wv.z * uv.z + wv.w * uv.w;
  }
  out[(size_t)(j * WIDTH + k) * MPTS + p] = sigf(acc);
}

// ------------- hidden layer: u1'[j][k][p] = sig(dot128(w[j][k], u1[j][:][p]))
// last=0: write fp32 [j][k][p]   last=1: write bf16 transposed [j][p][k] -----
__global__ __launch_bounds__(256) void k_layer_mid(const float* __restrict__ w,
                                                   const float* __restrict__ bias,
                                                   const float* __restrict__ in,
                                                   float* __restrict__ outf,
                                                   unsigned short* __restrict__ outbf,
                                                   int last) {
  int b = blockIdx.x;                      // 33*32 blocks
  int j = b >> 5;
  int k = ((b & 31) << 2) + (threadIdx.x >> 6);
  int p = threadIdx.x & 63;
  const float* wr = w + (size_t)(j * WIDTH + k) * WIDTH;
  const float* ip = in + (size_t)j * WIDTH * MPTS + p;
  float acc = bias[j * WIDTH + k];
#pragma unroll 4
  for (int l = 0; l < WIDTH; ++l) acc += wr[l] * ip[(size_t)l * MPTS];
  float s = sigf(acc);
  if (last) outbf[(size_t)(j * MPTS + p) * WIDTH + k] = f2bf(s);
  else      outf[(size_t)(j * WIDTH + k) * MPTS + p] = s;
}

// ------------- phase B: Gt2[j][p][m] = sig(dot128(wf[m][j], u1[j][:, p]) + bfin)
// MFMA per-j GEMM: C[m,p], A = wf (bf16-converted, LDS), B = u1bf[j] --------
__global__ __launch_bounds__(256) void k_final(const float* __restrict__ wf,
                                               const float* __restrict__ bfin,
                                               const unsigned short* __restrict__ u1bf,
                                               unsigned short* __restrict__ Gt2) {
  constexpr int KP = 136;                  // 128 + 8 pad (bank-conflict break)
  __shared__ unsigned short As[128 * KP];  // wf tile [m][k] bf16
  __shared__ unsigned short Bs[64 * KP];   // u1 [p][k] bf16
  int bid = blockIdx.x;                    // 33*16: j-major
  int j = bid >> 4;
  int m0 = (bid & 15) << 7;
  for (int c = threadIdx.x; c < 128 * 32; c += 256) {
    int row = c >> 5, f4 = c & 31;
    float4 v = *(const float4*)(wf + ((size_t)(m0 + row) * WIN + j) * WIDTH + (f4 << 2));
    ushort4 h;
    h.x = f2bf(v.x); h.y = f2bf(v.y); h.z = f2bf(v.z); h.w = f2bf(v.w);
    *(ushort4*)(&As[row * KP + (f4 << 2)]) = h;
  }
  for (int c = threadIdx.x; c < 64 * 16; c += 256) {
    int p = c >> 4, ch = c & 15;
    uint4 v = *(const uint4*)(u1bf + (size_t)(j * MPTS + p) * WIDTH + (ch << 3));
    *(uint4*)(&Bs[p * KP + (ch << 3)]) = v;
  }
  __syncthreads();
  int wv = threadIdx.x >> 6, lane = threadIdx.x & 63;
  int l15 = lane & 15, l4 = lane >> 4;
  f32x4 acc[2][4] = {};
#pragma unroll
  for (int t = 0; t < 4; ++t) {
    int col = (t << 5) + (l4 << 3);
    bf16x8 a[2], bb[4];
    a[0] = *(const bf16x8*)(&As[(wv * 32 + l15) * KP + col]);
    a[1] = *(const bf16x8*)(&As[(wv * 32 + 16 + l15) * KP + col]);
#pragma unroll
    for (int q = 0; q < 4; ++q)
      bb[q] = *(const bf16x8*)(&Bs[(q * 16 + l15) * KP + col]);
#pragma unroll
    for (int s = 0; s < 2; ++s)
#pragma unroll
      for (int q = 0; q < 4; ++q)
        acc[s][q] = __builtin_amdgcn_mfma_f32_16x16x32_bf16(a[s], bb[q], acc[s][q], 0, 0, 0);
  }
#pragma unroll
  for (int s = 0; s < 2; ++s)
#pragma unroll
    for (int q = 0; q < 4; ++q) {
      int mr = m0 + wv * 32 + s * 16 + (l4 << 2);   // 4 consecutive m per lane
      int p = q * 16 + l15;
      float z0 = acc[s][q][0] + bfin[(size_t)(mr + 0) * WIN + j];
      float z1 = acc[s][q][1] + bfin[(size_t)(mr + 1) * WIN + j];
      float z2 = acc[s][q][2] + bfin[(size_t)(mr + 2) * WIN + j];
      float z3 = acc[s][q][3] + bfin[(size_t)(mr + 3) * WIN + j];
      ushort4 st;
      st.x = f2bf(sigf(z0)); st.y = f2bf(sigf(z1));
      st.z = f2bf(sigf(z2)); st.w = f2bf(sigf(z3));
      *(ushort4*)(&Gt2[(size_t)(j * MPTS + p) * MM + mr]) = st;
    }
}

// ------------- phase C: out[n,p] += sum_{j,m} xiT[n+j,m] * Gt2[j][p][m] ----
// Block: 128n x 64p C-tile, m-split of 64, j-loop with shifted A reuse ------
__global__ __launch_bounds__(256) void k_conv(const unsigned short* __restrict__ xiT,
                                              const unsigned short* __restrict__ Gt2,
                                              float* __restrict__ out) {
  constexpr int AP = 72;                   // 64 + 8 pad
  __shared__ unsigned short As[160 * AP];  // xiT rows n0..n0+159, 64 m
  __shared__ unsigned short Bs[64 * AP];   // Gt2[j] 64p x 64m
  int bid = blockIdx.x;                    // 512 = 16 n-tiles x 32 m-splits
  int n0 = (bid & 15) << 7;
  int m0 = (bid >> 4) << 6;
  for (int c = threadIdx.x; c < 160 * 8; c += 256) {
    int row = c >> 3, mq = c & 7;
    uint4 v = *(const uint4*)(xiT + (size_t)(n0 + row) * MM + m0 + (mq << 3));
    *(uint4*)(&As[row * AP + (mq << 3)]) = v;
  }
  int wv = threadIdx.x >> 6, lane = threadIdx.x & 63;
  int l15 = lane & 15, l4 = lane >> 4;
  f32x4 acc[2][4] = {};
  for (int j = 0; j < WIN; ++j) {
    __syncthreads();   // j=0: covers A staging; j>0: protects Bs reuse
    for (int c = threadIdx.x; c < 64 * 8; c += 256) {
      int p = c >> 3, mq = c & 7;
      uint4 v = *(const uint4*)(Gt2 + (size_t)(j * MPTS + p) * MM + m0 + (mq << 3));
      *(uint4*)(&Bs[p * AP + (mq << 3)]) = v;
    }
    __syncthreads();
#pragma unroll
    for (int t = 0; t < 2; ++t) {
      int col = (t << 5) + (l4 << 3);
      bf16x8 a[2], bb[4];
      a[0] = *(const bf16x8*)(&As[(wv * 32 + l15 + j) * AP + col]);
      a[1] = *(const bf16x8*)(&As[(wv * 32 + 16 + l15 + j) * AP + col]);
#pragma unroll
      for (int q = 0; q < 4; ++q)
        bb[q] = *(const bf16x8*)(&Bs[(q * 16 + l15) * AP + col]);
#pragma unroll
      for (int s = 0; s < 2; ++s)
#pragma unroll
        for (int q = 0; q < 4; ++q)
          acc[s][q] = __builtin_amdgcn_mfma_f32_16x16x32_bf16(a[s], bb[q], acc[s][q], 0, 0, 0);
    }
  }
#pragma unroll
  for (int s = 0; s < 2; ++s)
#pragma unroll
    for (int q = 0; q < 4; ++q) {
      int nr = n0 + wv * 32 + s * 16 + (l4 << 2);
      int p = q * 16 + l15;
#pragma unroll
      for (int i = 0; i < 4; ++i)
        atomicAdd(&out[(size_t)(nr + i) * MPTS + p], acc[s][q][i]);
    }
}

extern "C" void kernel_launch(void* const* d_in, const int* in_sizes, int n_in,
                              void* d_out, int out_size, void* d_ws, size_t ws_size,
                              hipStream_t stream) {
  const float* u    = (const float*)d_in[0];  // [64,64]
  const float* w0   = (const float*)d_in[1];  // [33,128,64]
  const float* b0   = (const float*)d_in[2];  // [33,128,1]
  const float* w    = (const float*)d_in[3];  // [2,33,128,128]
  const float* bias = (const float*)d_in[4];  // [2,33,128,1]
  const float* wf   = (const float*)d_in[5];  // [2048,33,128]
  const float* bfin = (const float*)d_in[6];  // [2048,33,1]
  const float* xi   = (const float*)d_in[7];  // [2048,2080]
  float* out = (float*)d_out;                 // [2048,64]
  char* ws = (char*)d_ws;
  // workspace layout (all 16B-aligned offsets), total ~19.9 MB
  unsigned short* xiT  = (unsigned short*)(ws);             // 2080*2048*2   = 8,519,680
  unsigned short* Gt2  = (unsigned short*)(ws + 8519680);   // 33*64*2048*2  = 8,650,752
  float*          u1a  = (float*)(ws + 17170432);           // 33*128*64*4   = 1,081,344
  float*          u1b  = (float*)(ws + 18251776);           // 1,081,344
  unsigned short* u1bf = (unsigned short*)(ws + 19333120);  // 33*64*128*2   = 540,672

  hipMemsetAsync(out, 0, (size_t)out_size * sizeof(float), stream);
  k_transpose<<<dim3(65, 64), 256, 0, stream>>>(xi, xiT);
  k_layer0<<<33 * 32, 256, 0, stream>>>(u, w0, b0, u1a);
  k_layer_mid<<<33 * 32, 256, 0, stream>>>(w, bias, u1a, u1b, (unsigned short*)nullptr, 0);
  k_layer_mid<<<33 * 32, 256, 0, stream>>>(w + (size_t)WIN * WIDTH * WIDTH,
                                           bias + (size_t)WIN * WIDTH,
                                           u1b, (float*)nullptr, u1bf, 1);
  k_final<<<33 * 16, 256, 0, stream>>>(wf, bfin, u1bf, Gt2);
  k_conv<<<512, 256, 0, stream>>>(xiT, Gt2, out);
}